// Round 1
// baseline (1110.738 us; speedup 1.0000x reference)
//
#include <hip/hip_runtime.h>

#define NNODES 100000
#define NEDGES 1250000
#define IN_CH 128
#define HID 64
#define BN_EPS 1e-5f

// ---------------- degree ----------------
__global__ void deg_init(float* deg) {
    int i = blockIdx.x * blockDim.x + threadIdx.x;
    if (i < NNODES) deg[i] = 1.0f;   // self-loop
}

__global__ void deg_edges(const int* __restrict__ dst, float* deg) {
    int e = blockIdx.x * blockDim.x + threadIdx.x;
    if (e < NEDGES) atomicAdd(&deg[dst[e]], 1.0f);
}

__global__ void deg_to_dis(float* deg) {
    int i = blockIdx.x * blockDim.x + threadIdx.x;
    if (i < NNODES) deg[i] = rsqrtf(deg[i]);
}

// ---------------- fc + bn0 + relu ----------------
// h[i][j] = relu(bn0(sum_k x[i][k] * w[k][j] + b[j])); also stored as `last`
__global__ void fc_bn_relu(const float* __restrict__ x, const float* __restrict__ w,
                           const float* __restrict__ b,
                           const float* __restrict__ g, const float* __restrict__ be,
                           const float* __restrict__ mu, const float* __restrict__ var,
                           float* __restrict__ h, float* __restrict__ last) {
    int idx = blockIdx.x * blockDim.x + threadIdx.x;
    if (idx >= NNODES * HID) return;
    int i = idx >> 6;
    int j = idx & 63;
    const float4* x4 = (const float4*)(x + (size_t)i * IN_CH);
    float acc = 0.f;
#pragma unroll
    for (int k4 = 0; k4 < IN_CH / 4; ++k4) {
        float4 xv = x4[k4];
        int k = k4 * 4;
        acc = fmaf(xv.x, w[(k + 0) * HID + j], acc);
        acc = fmaf(xv.y, w[(k + 1) * HID + j], acc);
        acc = fmaf(xv.z, w[(k + 2) * HID + j], acc);
        acc = fmaf(xv.w, w[(k + 3) * HID + j], acc);
    }
    acc += b[j];
    float scale = g[j] * rsqrtf(var[j] + BN_EPS);
    float v = (acc - mu[j]) * scale + be[j];
    v = fmaxf(v, 0.f);
    h[idx] = v;
    last[idx] = v;
}

// ---------------- conv matmul + source-side dis scale ----------------
// hws[i][j] = dis[i] * sum_k h[i][k] * w[k][j];  agg initialized with the
// self-loop contribution (== hws[i][j]).
__global__ void conv_mm(const float* __restrict__ h, const float* __restrict__ w,
                        const float* __restrict__ dis,
                        float* __restrict__ hws, float* __restrict__ agg) {
    int idx = blockIdx.x * blockDim.x + threadIdx.x;
    if (idx >= NNODES * HID) return;
    int i = idx >> 6;
    int j = idx & 63;
    const float4* h4 = (const float4*)(h + (size_t)i * HID);
    float acc = 0.f;
#pragma unroll
    for (int k4 = 0; k4 < HID / 4; ++k4) {
        float4 hv = h4[k4];
        int k = k4 * 4;
        acc = fmaf(hv.x, w[(k + 0) * HID + j], acc);
        acc = fmaf(hv.y, w[(k + 1) * HID + j], acc);
        acc = fmaf(hv.z, w[(k + 2) * HID + j], acc);
        acc = fmaf(hv.w, w[(k + 3) * HID + j], acc);
    }
    float v = acc * dis[i];
    hws[idx] = v;
    agg[idx] = v;   // self-loop term
}

// ---------------- edge scatter ----------------
// one wave (64 lanes) per edge: lane j adds hws[s][j] into agg[d][j]
__global__ void scatter_edges(const int* __restrict__ src, const int* __restrict__ dst,
                              const float* __restrict__ hws, float* __restrict__ agg) {
    int t = blockIdx.x * blockDim.x + threadIdx.x;
    int e = t >> 6;
    int j = t & 63;
    if (e >= NEDGES) return;
    int s = src[e];
    int d = dst[e];
    atomicAdd(&agg[(size_t)d * HID + j], hws[(size_t)s * HID + j]);
}

// ---------------- layer epilogue ----------------
// h[i][j] = relu(bn_l(agg[i][j]*dis[i] + bias[j])) + last[i][j]
__global__ void layer_update(const float* __restrict__ agg, const float* __restrict__ dis,
                             const float* __restrict__ bias,
                             const float* __restrict__ g, const float* __restrict__ be,
                             const float* __restrict__ mu, const float* __restrict__ var,
                             const float* __restrict__ last, float* __restrict__ h) {
    int idx = blockIdx.x * blockDim.x + threadIdx.x;
    if (idx >= NNODES * HID) return;
    int i = idx >> 6;
    int j = idx & 63;
    float v = agg[idx] * dis[i] + bias[j];
    v = (v - mu[j]) * (g[j] * rsqrtf(var[j] + BN_EPS)) + be[j];
    v = fmaxf(v, 0.f) + last[idx];
    h[idx] = v;
}

extern "C" void kernel_launch(void* const* d_in, const int* in_sizes, int n_in,
                              void* d_out, int out_size, void* d_ws, size_t ws_size,
                              hipStream_t stream) {
    const float* x      = (const float*)d_in[0];
    const int*   eidx   = (const int*)d_in[1];   // [2, E] row-major
    const float* fc_w   = (const float*)d_in[2];
    const float* fc_b   = (const float*)d_in[3];
    const float* conv_w = (const float*)d_in[4]; // [L, 64, 64]
    const float* conv_b = (const float*)d_in[5]; // [L, 64]
    const float* bn_g   = (const float*)d_in[6]; // [L+1, 64]
    const float* bn_b   = (const float*)d_in[7];
    const float* bn_m   = (const float*)d_in[8];
    const float* bn_v   = (const float*)d_in[9];

    const int* src = eidx;            // edge_index[0]
    const int* dst = eidx + NEDGES;   // edge_index[1]

    float* h = (float*)d_out;         // running node features [N, 64]

    // workspace layout (all float): dis | last | hws | agg
    float* dis  = (float*)d_ws;
    float* last = dis + 100352;               // N rounded up to 256B align
    float* hws  = last + (size_t)NNODES * HID;
    float* agg  = hws + (size_t)NNODES * HID;

    const int BLK = 256;
    const int gridN   = (NNODES + BLK - 1) / BLK;
    const int gridE   = (NEDGES + BLK - 1) / BLK;
    const int gridNH  = (NNODES * HID + BLK - 1) / BLK;
    const int gridE64 = (NEDGES * 64 + BLK - 1) / BLK;  // 80M threads / 256

    // degree -> dis (in place)
    deg_init<<<gridN, BLK, 0, stream>>>(dis);
    deg_edges<<<gridE, BLK, 0, stream>>>(dst, dis);
    deg_to_dis<<<gridN, BLK, 0, stream>>>(dis);

    // fc + bn0 + relu -> h (d_out) and last
    fc_bn_relu<<<gridNH, BLK, 0, stream>>>(x, fc_w, fc_b,
                                           bn_g, bn_b, bn_m, bn_v,
                                           h, last);

    for (int l = 0; l < 2; ++l) {
        const float* w    = conv_w + (size_t)l * HID * HID;
        const float* bias = conv_b + (size_t)l * HID;
        const float* g    = bn_g + (size_t)(l + 1) * HID;
        const float* be   = bn_b + (size_t)(l + 1) * HID;
        const float* mu   = bn_m + (size_t)(l + 1) * HID;
        const float* var  = bn_v + (size_t)(l + 1) * HID;

        conv_mm<<<gridNH, BLK, 0, stream>>>(h, w, dis, hws, agg);
        scatter_edges<<<gridE64, BLK, 0, stream>>>(src, dst, hws, agg);
        layer_update<<<gridNH, BLK, 0, stream>>>(agg, dis, bias, g, be, mu, var, last, h);
    }
}

// Round 2
// 743.822 us; speedup vs baseline: 1.4933x; 1.4933x over previous
//
#include <hip/hip_runtime.h>

#define NNODES 100000
#define NEDGES 1250000
#define IN_CH 128
#define HID 64
#define BN_EPS 1e-5f

#define NPAD 100352               // NNODES rounded up (alignment)
#define NSCAN_BLOCKS 391          // ceil(100000/256)

// ---------------- CSR build ----------------
__global__ void csr_zero(int* cnt) {
    int i = blockIdx.x * blockDim.x + threadIdx.x;
    if (i < NNODES) cnt[i] = 0;
}

__global__ void csr_count(const int* __restrict__ dst, int* cnt) {
    int e = blockIdx.x * blockDim.x + threadIdx.x;
    if (e < NEDGES) atomicAdd(&cnt[dst[e]], 1);
}

// per-256-block exclusive scan of cnt -> row_ptr, block sums -> bsum.
// Also emits dis[i] = rsqrt(cnt[i]+1)  (degree incl. self-loop).
__global__ void scan1(const int* __restrict__ cnt, int* __restrict__ row_ptr,
                      int* __restrict__ bsum, float* __restrict__ dis) {
    __shared__ int s[256];
    int tid = threadIdx.x;
    int i = blockIdx.x * 256 + tid;
    int v = (i < NNODES) ? cnt[i] : 0;
    if (i < NNODES) dis[i] = rsqrtf((float)(v + 1));
    s[tid] = v;
    __syncthreads();
    for (int off = 1; off < 256; off <<= 1) {
        int t = (tid >= off) ? s[tid - off] : 0;
        __syncthreads();
        s[tid] += t;
        __syncthreads();
    }
    if (i < NNODES) row_ptr[i] = s[tid] - v;          // exclusive
    if (tid == 255) bsum[blockIdx.x] = s[255];        // block total
}

// single-block exclusive scan of the 391 block sums (512 threads, padded)
__global__ void scan2(int* bsum) {
    __shared__ int s[512];
    int tid = threadIdx.x;
    int v = (tid < NSCAN_BLOCKS) ? bsum[tid] : 0;
    s[tid] = v;
    __syncthreads();
    for (int off = 1; off < 512; off <<= 1) {
        int t = (tid >= off) ? s[tid - off] : 0;
        __syncthreads();
        s[tid] += t;
        __syncthreads();
    }
    if (tid < NSCAN_BLOCKS) bsum[tid] = s[tid] - v;   // exclusive
}

__global__ void scan3(int* __restrict__ row_ptr, const int* __restrict__ bsum,
                      int* __restrict__ pos) {
    int i = blockIdx.x * blockDim.x + threadIdx.x;
    if (i < NNODES) {
        int v = row_ptr[i] + bsum[i >> 8];
        row_ptr[i] = v;
        pos[i] = v;
    }
}

__global__ void csr_fill(const int* __restrict__ src, const int* __restrict__ dst,
                         int* pos, int* __restrict__ srcs) {
    int e = blockIdx.x * blockDim.x + threadIdx.x;
    if (e < NEDGES) {
        int slot = atomicAdd(&pos[dst[e]], 1);
        srcs[slot] = src[e];
    }
}

// ---------------- fc + bn0 + relu ----------------
__global__ void fc_bn_relu(const float* __restrict__ x, const float* __restrict__ w,
                           const float* __restrict__ b,
                           const float* __restrict__ g, const float* __restrict__ be,
                           const float* __restrict__ mu, const float* __restrict__ var,
                           float* __restrict__ h, float* __restrict__ last) {
    int idx = blockIdx.x * blockDim.x + threadIdx.x;
    if (idx >= NNODES * HID) return;
    int i = idx >> 6;
    int j = idx & 63;
    const float4* x4 = (const float4*)(x + (size_t)i * IN_CH);
    float acc = 0.f;
#pragma unroll
    for (int k4 = 0; k4 < IN_CH / 4; ++k4) {
        float4 xv = x4[k4];
        int k = k4 * 4;
        acc = fmaf(xv.x, w[(k + 0) * HID + j], acc);
        acc = fmaf(xv.y, w[(k + 1) * HID + j], acc);
        acc = fmaf(xv.z, w[(k + 2) * HID + j], acc);
        acc = fmaf(xv.w, w[(k + 3) * HID + j], acc);
    }
    acc += b[j];
    float scale = g[j] * rsqrtf(var[j] + BN_EPS);
    float v = (acc - mu[j]) * scale + be[j];
    v = fmaxf(v, 0.f);
    h[idx] = v;
    last[idx] = v;
}

// ---------------- conv matmul + source-side dis scale ----------------
// hws[i][j] = dis[i] * sum_k h[i][k] * w[k][j]
__global__ void conv_mm(const float* __restrict__ h, const float* __restrict__ w,
                        const float* __restrict__ dis, float* __restrict__ hws) {
    int idx = blockIdx.x * blockDim.x + threadIdx.x;
    if (idx >= NNODES * HID) return;
    int i = idx >> 6;
    int j = idx & 63;
    const float4* h4 = (const float4*)(h + (size_t)i * HID);
    float acc = 0.f;
#pragma unroll
    for (int k4 = 0; k4 < HID / 4; ++k4) {
        float4 hv = h4[k4];
        int k = k4 * 4;
        acc = fmaf(hv.x, w[(k + 0) * HID + j], acc);
        acc = fmaf(hv.y, w[(k + 1) * HID + j], acc);
        acc = fmaf(hv.z, w[(k + 2) * HID + j], acc);
        acc = fmaf(hv.w, w[(k + 3) * HID + j], acc);
    }
    hws[idx] = acc * dis[i];
}

// ---------------- gather + epilogue (one wave per dst node) ----------------
// agg_j = hws[d][j] (self loop) + sum_{incoming e} hws[src(e)][j]
// h[d][j] = relu(bn(agg_j*dis[d] + bias[j])) + last[d][j]
__global__ void gather_update(const float* __restrict__ hws,
                              const int* __restrict__ row_ptr, const int* __restrict__ cnt,
                              const int* __restrict__ srcs, const float* __restrict__ dis,
                              const float* __restrict__ bias,
                              const float* __restrict__ g, const float* __restrict__ be,
                              const float* __restrict__ mu, const float* __restrict__ var,
                              const float* __restrict__ last, float* __restrict__ h) {
    int t = blockIdx.x * blockDim.x + threadIdx.x;
    int d = t >> 6;
    if (d >= NNODES) return;
    int j = t & 63;

    float acc = hws[(size_t)d * HID + j];     // self-loop (source-side dis[d] applied)
    int start = row_ptr[d];
    int n = cnt[d];
    const int* sp = srcs + start;

    int k = 0;
    for (; k + 3 < n; k += 4) {               // unroll 4 for load ILP
        int s0 = sp[k + 0], s1 = sp[k + 1], s2 = sp[k + 2], s3 = sp[k + 3];
        float v0 = hws[(size_t)s0 * HID + j];
        float v1 = hws[(size_t)s1 * HID + j];
        float v2 = hws[(size_t)s2 * HID + j];
        float v3 = hws[(size_t)s3 * HID + j];
        acc += v0 + v1 + v2 + v3;
    }
    for (; k < n; ++k) acc += hws[(size_t)sp[k] * HID + j];

    float v = acc * dis[d] + bias[j];
    v = (v - mu[j]) * (g[j] * rsqrtf(var[j] + BN_EPS)) + be[j];
    h[(size_t)d * HID + j] = fmaxf(v, 0.f) + last[(size_t)d * HID + j];
}

extern "C" void kernel_launch(void* const* d_in, const int* in_sizes, int n_in,
                              void* d_out, int out_size, void* d_ws, size_t ws_size,
                              hipStream_t stream) {
    const float* x      = (const float*)d_in[0];
    const int*   eidx   = (const int*)d_in[1];
    const float* fc_w   = (const float*)d_in[2];
    const float* fc_b   = (const float*)d_in[3];
    const float* conv_w = (const float*)d_in[4];
    const float* conv_b = (const float*)d_in[5];
    const float* bn_g   = (const float*)d_in[6];
    const float* bn_b   = (const float*)d_in[7];
    const float* bn_m   = (const float*)d_in[8];
    const float* bn_v   = (const float*)d_in[9];

    const int* src = eidx;
    const int* dst = eidx + NEDGES;

    float* h = (float*)d_out;

    // workspace layout (4B elems): dis | cnt | row_ptr | pos | bsum | srcs | last | hws
    float* dis     = (float*)d_ws;
    int*   cnt     = (int*)(dis + NPAD);
    int*   row_ptr = cnt + NPAD;
    int*   pos     = row_ptr + NPAD;
    int*   bsum    = pos + NPAD;
    int*   srcs    = bsum + 512;
    float* last    = (float*)(srcs + NEDGES) + 48;   // re-align to 256B
    float* hws     = last + (size_t)NNODES * HID;

    const int BLK = 256;
    const int gridN  = (NNODES + BLK - 1) / BLK;
    const int gridE  = (NEDGES + BLK - 1) / BLK;
    const int gridNH = (NNODES * HID + BLK - 1) / BLK;

    // CSR build + degree
    csr_zero<<<gridN, BLK, 0, stream>>>(cnt);
    csr_count<<<gridE, BLK, 0, stream>>>(dst, cnt);
    scan1<<<NSCAN_BLOCKS, 256, 0, stream>>>(cnt, row_ptr, bsum, dis);
    scan2<<<1, 512, 0, stream>>>(bsum);
    scan3<<<gridN, BLK, 0, stream>>>(row_ptr, bsum, pos);
    csr_fill<<<gridE, BLK, 0, stream>>>(src, dst, pos, srcs);

    // fc + bn0 + relu
    fc_bn_relu<<<gridNH, BLK, 0, stream>>>(x, fc_w, fc_b, bn_g, bn_b, bn_m, bn_v,
                                           h, last);

    for (int l = 0; l < 2; ++l) {
        const float* w    = conv_w + (size_t)l * HID * HID;
        const float* bias = conv_b + (size_t)l * HID;
        const float* g    = bn_g + (size_t)(l + 1) * HID;
        const float* be   = bn_b + (size_t)(l + 1) * HID;
        const float* mu   = bn_m + (size_t)(l + 1) * HID;
        const float* var  = bn_v + (size_t)(l + 1) * HID;

        conv_mm<<<gridNH, BLK, 0, stream>>>(h, w, dis, hws);
        gather_update<<<gridNH, BLK, 0, stream>>>(hws, row_ptr, cnt, srcs, dis,
                                                  bias, g, be, mu, var, last, h);
    }
}

// Round 3
// 490.083 us; speedup vs baseline: 2.2664x; 1.5177x over previous
//
#include <hip/hip_runtime.h>

#define NNODES 100000
#define NEDGES 1250000
#define IN_CH 128
#define HID 64
#define BN_EPS 1e-5f

#define NPAD 100352               // NNODES rounded up (alignment)
#define NSCAN_BLOCKS 391          // ceil(100000/256)

// ---------------- CSR build ----------------
__global__ void csr_zero(int* cnt) {
    int i = blockIdx.x * blockDim.x + threadIdx.x;
    if (i < NNODES) cnt[i] = 0;
}

__global__ void csr_count(const int* __restrict__ dst, int* cnt) {
    int e = blockIdx.x * blockDim.x + threadIdx.x;
    if (e < NEDGES) atomicAdd(&cnt[dst[e]], 1);
}

// per-256-block exclusive scan of cnt -> row_ptr, block sums -> bsum.
// Also emits dis[i] = rsqrt(cnt[i]+1)  (degree incl. self-loop).
__global__ void scan1(const int* __restrict__ cnt, int* __restrict__ row_ptr,
                      int* __restrict__ bsum, float* __restrict__ dis) {
    __shared__ int s[256];
    int tid = threadIdx.x;
    int i = blockIdx.x * 256 + tid;
    int v = (i < NNODES) ? cnt[i] : 0;
    if (i < NNODES) dis[i] = rsqrtf((float)(v + 1));
    s[tid] = v;
    __syncthreads();
    for (int off = 1; off < 256; off <<= 1) {
        int t = (tid >= off) ? s[tid - off] : 0;
        __syncthreads();
        s[tid] += t;
        __syncthreads();
    }
    if (i < NNODES) row_ptr[i] = s[tid] - v;          // exclusive
    if (tid == 255) bsum[blockIdx.x] = s[255];        // block total
}

// single-block exclusive scan of the 391 block sums (512 threads, padded)
__global__ void scan2(int* bsum) {
    __shared__ int s[512];
    int tid = threadIdx.x;
    int v = (tid < NSCAN_BLOCKS) ? bsum[tid] : 0;
    s[tid] = v;
    __syncthreads();
    for (int off = 1; off < 512; off <<= 1) {
        int t = (tid >= off) ? s[tid - off] : 0;
        __syncthreads();
        s[tid] += t;
        __syncthreads();
    }
    if (tid < NSCAN_BLOCKS) bsum[tid] = s[tid] - v;   // exclusive
}

__global__ void scan3(int* __restrict__ row_ptr, const int* __restrict__ bsum,
                      int* __restrict__ pos) {
    int i = blockIdx.x * blockDim.x + threadIdx.x;
    if (i < NNODES) {
        int v = row_ptr[i] + bsum[i >> 8];
        row_ptr[i] = v;
        pos[i] = v;
    }
}

__global__ void csr_fill(const int* __restrict__ src, const int* __restrict__ dst,
                         int* pos, int* __restrict__ srcs) {
    int e = blockIdx.x * blockDim.x + threadIdx.x;
    if (e < NEDGES) {
        int slot = atomicAdd(&pos[dst[e]], 1);
        srcs[slot] = src[e];
    }
}

// ---------------- fc + bn0 + relu (register-tiled 4 nodes x 4 outputs) ----
// h0[i][j] = relu(bn0(sum_k x[i][k]*w[k][j] + b[j]))
__global__ __launch_bounds__(256) void fc_bn_relu(
        const float* __restrict__ x, const float* __restrict__ w,
        const float* __restrict__ b,
        const float* __restrict__ g, const float* __restrict__ be,
        const float* __restrict__ mu, const float* __restrict__ var,
        float* __restrict__ h0) {
    const int jg = threadIdx.x & 15;          // output group: j = 4*jg .. 4*jg+3
    const int ig = threadIdx.x >> 4;          // node group within block
    const int ibase = blockIdx.x * 64 + ig * 4;
    const int j4 = jg * 4;

    float4 acc0 = {0,0,0,0}, acc1 = {0,0,0,0}, acc2 = {0,0,0,0}, acc3 = {0,0,0,0};

    int i0 = (ibase + 0 < NNODES) ? ibase + 0 : NNODES - 1;
    int i1 = (ibase + 1 < NNODES) ? ibase + 1 : NNODES - 1;
    int i2 = (ibase + 2 < NNODES) ? ibase + 2 : NNODES - 1;
    int i3 = (ibase + 3 < NNODES) ? ibase + 3 : NNODES - 1;
    const float4* x0 = (const float4*)(x + (size_t)i0 * IN_CH);
    const float4* x1 = (const float4*)(x + (size_t)i1 * IN_CH);
    const float4* x2 = (const float4*)(x + (size_t)i2 * IN_CH);
    const float4* x3 = (const float4*)(x + (size_t)i3 * IN_CH);
    const float4* w4 = (const float4*)w;      // index: k*16 + jg

#pragma unroll 8
    for (int k4 = 0; k4 < IN_CH / 4; ++k4) {
        float4 wv0 = w4[(4*k4 + 0) * 16 + jg];
        float4 wv1 = w4[(4*k4 + 1) * 16 + jg];
        float4 wv2 = w4[(4*k4 + 2) * 16 + jg];
        float4 wv3 = w4[(4*k4 + 3) * 16 + jg];
        float4 xv;
#define ROW(xr, accr) \
        xv = xr[k4]; \
        accr.x = fmaf(xv.x, wv0.x, accr.x); accr.y = fmaf(xv.x, wv0.y, accr.y); \
        accr.z = fmaf(xv.x, wv0.z, accr.z); accr.w = fmaf(xv.x, wv0.w, accr.w); \
        accr.x = fmaf(xv.y, wv1.x, accr.x); accr.y = fmaf(xv.y, wv1.y, accr.y); \
        accr.z = fmaf(xv.y, wv1.z, accr.z); accr.w = fmaf(xv.y, wv1.w, accr.w); \
        accr.x = fmaf(xv.z, wv2.x, accr.x); accr.y = fmaf(xv.z, wv2.y, accr.y); \
        accr.z = fmaf(xv.z, wv2.z, accr.z); accr.w = fmaf(xv.z, wv2.w, accr.w); \
        accr.x = fmaf(xv.w, wv3.x, accr.x); accr.y = fmaf(xv.w, wv3.y, accr.y); \
        accr.z = fmaf(xv.w, wv3.z, accr.z); accr.w = fmaf(xv.w, wv3.w, accr.w);
        ROW(x0, acc0) ROW(x1, acc1) ROW(x2, acc2) ROW(x3, acc3)
#undef ROW
    }

    float4 bv  = *(const float4*)(b + j4);
    float4 gv  = *(const float4*)(g + j4);
    float4 bev = *(const float4*)(be + j4);
    float4 muv = *(const float4*)(mu + j4);
    float4 vav = *(const float4*)(var + j4);
    float4 sc;
    sc.x = gv.x * rsqrtf(vav.x + BN_EPS);
    sc.y = gv.y * rsqrtf(vav.y + BN_EPS);
    sc.z = gv.z * rsqrtf(vav.z + BN_EPS);
    sc.w = gv.w * rsqrtf(vav.w + BN_EPS);

#define EPI(accr, r) \
    if (ibase + r < NNODES) { \
        float4 v; \
        v.x = fmaxf((accr.x + bv.x - muv.x) * sc.x + bev.x, 0.f); \
        v.y = fmaxf((accr.y + bv.y - muv.y) * sc.y + bev.y, 0.f); \
        v.z = fmaxf((accr.z + bv.z - muv.z) * sc.z + bev.z, 0.f); \
        v.w = fmaxf((accr.w + bv.w - muv.w) * sc.w + bev.w, 0.f); \
        *(float4*)(h0 + (size_t)(ibase + r) * HID + j4) = v; \
    }
    EPI(acc0, 0) EPI(acc1, 1) EPI(acc2, 2) EPI(acc3, 3)
#undef EPI
}

// ---------------- conv matmul + source-side dis scale (register-tiled) ----
// hws[i][j] = dis[i] * sum_k h[i][k] * w[k][j]
__global__ __launch_bounds__(256) void conv_mm(
        const float* __restrict__ h, const float* __restrict__ w,
        const float* __restrict__ dis, float* __restrict__ hws) {
    const int jg = threadIdx.x & 15;
    const int ig = threadIdx.x >> 4;
    const int ibase = blockIdx.x * 64 + ig * 4;
    const int j4 = jg * 4;

    float4 acc0 = {0,0,0,0}, acc1 = {0,0,0,0}, acc2 = {0,0,0,0}, acc3 = {0,0,0,0};

    int i0 = (ibase + 0 < NNODES) ? ibase + 0 : NNODES - 1;
    int i1 = (ibase + 1 < NNODES) ? ibase + 1 : NNODES - 1;
    int i2 = (ibase + 2 < NNODES) ? ibase + 2 : NNODES - 1;
    int i3 = (ibase + 3 < NNODES) ? ibase + 3 : NNODES - 1;
    const float4* h0p = (const float4*)(h + (size_t)i0 * HID);
    const float4* h1p = (const float4*)(h + (size_t)i1 * HID);
    const float4* h2p = (const float4*)(h + (size_t)i2 * HID);
    const float4* h3p = (const float4*)(h + (size_t)i3 * HID);
    const float4* w4 = (const float4*)w;

#pragma unroll 8
    for (int k4 = 0; k4 < HID / 4; ++k4) {
        float4 wv0 = w4[(4*k4 + 0) * 16 + jg];
        float4 wv1 = w4[(4*k4 + 1) * 16 + jg];
        float4 wv2 = w4[(4*k4 + 2) * 16 + jg];
        float4 wv3 = w4[(4*k4 + 3) * 16 + jg];
        float4 xv;
#define ROW(xr, accr) \
        xv = xr[k4]; \
        accr.x = fmaf(xv.x, wv0.x, accr.x); accr.y = fmaf(xv.x, wv0.y, accr.y); \
        accr.z = fmaf(xv.x, wv0.z, accr.z); accr.w = fmaf(xv.x, wv0.w, accr.w); \
        accr.x = fmaf(xv.y, wv1.x, accr.x); accr.y = fmaf(xv.y, wv1.y, accr.y); \
        accr.z = fmaf(xv.y, wv1.z, accr.z); accr.w = fmaf(xv.y, wv1.w, accr.w); \
        accr.x = fmaf(xv.z, wv2.x, accr.x); accr.y = fmaf(xv.z, wv2.y, accr.y); \
        accr.z = fmaf(xv.z, wv2.z, accr.z); accr.w = fmaf(xv.z, wv2.w, accr.w); \
        accr.x = fmaf(xv.w, wv3.x, accr.x); accr.y = fmaf(xv.w, wv3.y, accr.y); \
        accr.z = fmaf(xv.w, wv3.z, accr.z); accr.w = fmaf(xv.w, wv3.w, accr.w);
        ROW(h0p, acc0) ROW(h1p, acc1) ROW(h2p, acc2) ROW(h3p, acc3)
#undef ROW
    }

#define EPI(accr, ir, r) \
    if (ibase + r < NNODES) { \
        float dv = dis[ir]; \
        float4 v; v.x = accr.x * dv; v.y = accr.y * dv; v.z = accr.z * dv; v.w = accr.w * dv; \
        *(float4*)(hws + (size_t)(ibase + r) * HID + j4) = v; \
    }
    EPI(acc0, i0, 0) EPI(acc1, i1, 1) EPI(acc2, i2, 2) EPI(acc3, i3, 3)
#undef EPI
}

// ---------------- gather + epilogue (one wave per dst node) ----------------
// agg_j = hws[d][j] (self loop) + sum_{incoming e} hws[src(e)][j]
// hout[d][j] = relu(bn(agg_j*dis[d] + bias[j])) + last[d][j]
__global__ void gather_update(const float* __restrict__ hws,
                              const int* __restrict__ row_ptr, const int* __restrict__ cnt,
                              const int* __restrict__ srcs, const float* __restrict__ dis,
                              const float* __restrict__ bias,
                              const float* __restrict__ g, const float* __restrict__ be,
                              const float* __restrict__ mu, const float* __restrict__ var,
                              const float* __restrict__ last, float* __restrict__ hout) {
    int t = blockIdx.x * blockDim.x + threadIdx.x;
    int d = t >> 6;
    if (d >= NNODES) return;
    int j = t & 63;

    float acc = hws[(size_t)d * HID + j];     // self-loop (source-side dis[d] applied)
    int start = row_ptr[d];
    int n = cnt[d];
    const int* sp = srcs + start;

    int k = 0;
    for (; k + 3 < n; k += 4) {               // unroll 4 for load ILP
        int s0 = sp[k + 0], s1 = sp[k + 1], s2 = sp[k + 2], s3 = sp[k + 3];
        float v0 = hws[(size_t)s0 * HID + j];
        float v1 = hws[(size_t)s1 * HID + j];
        float v2 = hws[(size_t)s2 * HID + j];
        float v3 = hws[(size_t)s3 * HID + j];
        acc += v0 + v1 + v2 + v3;
    }
    for (; k < n; ++k) acc += hws[(size_t)sp[k] * HID + j];

    float v = acc * dis[d] + bias[j];
    v = (v - mu[j]) * (g[j] * rsqrtf(var[j] + BN_EPS)) + be[j];
    hout[(size_t)d * HID + j] = fmaxf(v, 0.f) + last[(size_t)d * HID + j];
}

extern "C" void kernel_launch(void* const* d_in, const int* in_sizes, int n_in,
                              void* d_out, int out_size, void* d_ws, size_t ws_size,
                              hipStream_t stream) {
    const float* x      = (const float*)d_in[0];
    const int*   eidx   = (const int*)d_in[1];
    const float* fc_w   = (const float*)d_in[2];
    const float* fc_b   = (const float*)d_in[3];
    const float* conv_w = (const float*)d_in[4];
    const float* conv_b = (const float*)d_in[5];
    const float* bn_g   = (const float*)d_in[6];
    const float* bn_b   = (const float*)d_in[7];
    const float* bn_m   = (const float*)d_in[8];
    const float* bn_v   = (const float*)d_in[9];

    const int* src = eidx;
    const int* dst = eidx + NEDGES;

    float* hio = (float*)d_out;       // serves as h1 (layer-1 out) and final out

    // workspace layout (4B elems): dis | cnt | row_ptr | pos | bsum | srcs | h0 | hws
    float* dis     = (float*)d_ws;
    int*   cnt     = (int*)(dis + NPAD);
    int*   row_ptr = cnt + NPAD;
    int*   pos     = row_ptr + NPAD;
    int*   bsum    = pos + NPAD;
    int*   srcs    = bsum + 512;
    float* h0      = (float*)(srcs + NEDGES) + 48;   // re-align; residual `last`
    float* hws     = h0 + (size_t)NNODES * HID;

    const int BLK = 256;
    const int gridN  = (NNODES + BLK - 1) / BLK;
    const int gridE  = (NEDGES + BLK - 1) / BLK;
    const int gridNH = (NNODES * HID + BLK - 1) / BLK;   // 25000 (gather)
    const int gridMM = (NNODES + 63) / 64;               // 1563 (tiled matmuls)

    // CSR build + degree
    csr_zero<<<gridN, BLK, 0, stream>>>(cnt);
    csr_count<<<gridE, BLK, 0, stream>>>(dst, cnt);
    scan1<<<NSCAN_BLOCKS, 256, 0, stream>>>(cnt, row_ptr, bsum, dis);
    scan2<<<1, 512, 0, stream>>>(bsum);
    scan3<<<gridN, BLK, 0, stream>>>(row_ptr, bsum, pos);
    csr_fill<<<gridE, BLK, 0, stream>>>(src, dst, pos, srcs);

    // fc + bn0 + relu -> h0 (residual). h0 is never overwritten.
    fc_bn_relu<<<gridMM, BLK, 0, stream>>>(x, fc_w, fc_b, bn_g, bn_b, bn_m, bn_v, h0);

    // layer 1: h0 -> hws -> hio
    conv_mm<<<gridMM, BLK, 0, stream>>>(h0, conv_w, dis, hws);
    gather_update<<<gridNH, BLK, 0, stream>>>(hws, row_ptr, cnt, srcs, dis,
                                              conv_b, bn_g + HID, bn_b + HID,
                                              bn_m + HID, bn_v + HID, h0, hio);

    // layer 2: hio -> hws -> hio (final output)
    conv_mm<<<gridMM, BLK, 0, stream>>>(hio, conv_w + HID * HID, dis, hws);
    gather_update<<<gridNH, BLK, 0, stream>>>(hws, row_ptr, cnt, srcs, dis,
                                              conv_b + HID, bn_g + 2 * HID, bn_b + 2 * HID,
                                              bn_m + 2 * HID, bn_v + 2 * HID, h0, hio);
}